// Round 1
// baseline (788.204 us; speedup 1.0000x reference)
//
#include <hip/hip_runtime.h>
#include <hip/hip_bf16.h>

// ---------------- graph build ----------------

__global__ void count_k(const int* __restrict__ src, const int* __restrict__ dst,
                        int* __restrict__ cntS, int* __restrict__ cntD, int E) {
    int i = blockIdx.x * blockDim.x + threadIdx.x;
    int stride = gridDim.x * blockDim.x;
    for (; i < E; i += stride) {
        atomicAdd(&cntS[src[i]], 1);
        atomicAdd(&cntD[dst[i]], 1);
    }
}

__global__ void dinv_k(const int* __restrict__ cntS, float* __restrict__ dinv, int n) {
    int i = blockIdx.x * blockDim.x + threadIdx.x;
    if (i < n) dinv[i] = rsqrtf((float)(1 + cntS[i]));
}

__global__ void scan1_k(const int* __restrict__ cntD, int* __restrict__ bsum, int n) {
    __shared__ int ls[256];
    int b = blockIdx.x, t = threadIdx.x;
    int i0 = b * 1024 + t * 4;
    int s = 0;
#pragma unroll
    for (int j = 0; j < 4; j++) { int idx = i0 + j; if (idx < n) s += cntD[idx]; }
    ls[t] = s; __syncthreads();
    for (int off = 128; off; off >>= 1) { if (t < off) ls[t] += ls[t + off]; __syncthreads(); }
    if (t == 0) bsum[b] = ls[0];
}

__global__ void scan2_k(const int* __restrict__ bsum, int* __restrict__ boff, int nb) {
    __shared__ int ls[256];
    int t = threadIdx.x;
    int v = (t < nb) ? bsum[t] : 0;
    ls[t] = v; __syncthreads();
    for (int off = 1; off < 256; off <<= 1) {
        int u = (t >= off) ? ls[t - off] : 0;
        __syncthreads();
        ls[t] += u;
        __syncthreads();
    }
    if (t < nb) boff[t] = ls[t] - v;  // exclusive
}

__global__ void scan3_k(const int* __restrict__ cntD, const int* __restrict__ boff,
                        int* __restrict__ rowPtr, int n) {
    __shared__ int ls[256];
    int b = blockIdx.x, t = threadIdx.x;
    int i0 = b * 1024 + t * 4;
    int c[4]; int s = 0;
#pragma unroll
    for (int j = 0; j < 4; j++) { c[j] = (i0 + j < n) ? cntD[i0 + j] : 0; s += c[j]; }
    ls[t] = s; __syncthreads();
    for (int off = 1; off < 256; off <<= 1) {
        int u = (t >= off) ? ls[t - off] : 0;
        __syncthreads();
        ls[t] += u;
        __syncthreads();
    }
    int run = ls[t] - s + boff[b];
#pragma unroll
    for (int j = 0; j < 4; j++) {
        if (i0 + j < n) rowPtr[i0 + j] = run;
        run += c[j];
    }
}

__global__ void fill_k(const int* __restrict__ src, const int* __restrict__ dst,
                       const int* __restrict__ rowPtr, int* __restrict__ tmp,
                       int* __restrict__ col, int E) {
    int i = blockIdx.x * blockDim.x + threadIdx.x;
    int stride = gridDim.x * blockDim.x;
    for (; i < E; i += stride) {
        int d = dst[i];
        int pos = rowPtr[d] + atomicAdd(&tmp[d], 1);
        col[pos] = src[i];
    }
}

// ---------------- GEMM1: h = X @ W1 + b1  (X: n x 512, W1: 512 x 16) ----------------

#define KCH 32
#define XTS 258  // LDS row stride (floats) -> bank (2k + r) % 32: conflict-free reads, 2-way writes

__global__ __launch_bounds__(256) void gemm1_k(const float* __restrict__ X,
                                               const float* __restrict__ W,
                                               const float* __restrict__ B,
                                               float* __restrict__ H, int n) {
    __shared__ float xt[KCH * XTS];   // 33 KB, transposed tile xt[k][row]
    __shared__ float wc[KCH * 16];    // 2 KB
    int t = threadIdx.x;
    int rowBase = blockIdx.x * 256;
    int myRow = rowBase + t;
    int srow = t >> 3, skq = t & 7;   // staging: row = p*32+srow, k-quad = skq

    float acc[16];
#pragma unroll
    for (int c = 0; c < 16; c++) acc[c] = 0.f;

    float4 xreg[8];
#pragma unroll
    for (int p = 0; p < 8; p++) {
        int gr = rowBase + p * 32 + srow;
        xreg[p] = (gr < n) ? *(const float4*)&X[(size_t)gr * 512 + skq * 4]
                           : float4{0.f, 0.f, 0.f, 0.f};
    }

    for (int ch = 0; ch < 16; ++ch) {
        int k0 = ch * KCH;
        // write staged regs -> LDS (transposed)
#pragma unroll
        for (int p = 0; p < 8; p++) {
            int r = p * 32 + srow;
            int kb = skq * 4;
            xt[(kb + 0) * XTS + r] = xreg[p].x;
            xt[(kb + 1) * XTS + r] = xreg[p].y;
            xt[(kb + 2) * XTS + r] = xreg[p].z;
            xt[(kb + 3) * XTS + r] = xreg[p].w;
        }
        wc[t] = W[k0 * 16 + t];
        wc[256 + t] = W[k0 * 16 + 256 + t];
        __syncthreads();

        // prefetch next chunk into regs (overlaps with compute below)
        if (ch < 15) {
            int k0n = k0 + KCH;
#pragma unroll
            for (int p = 0; p < 8; p++) {
                int gr = rowBase + p * 32 + srow;
                xreg[p] = (gr < n) ? *(const float4*)&X[(size_t)gr * 512 + k0n + skq * 4]
                                   : float4{0.f, 0.f, 0.f, 0.f};
            }
        }

#pragma unroll
        for (int k = 0; k < KCH; k++) {
            float xv = xt[k * XTS + t];
            const float4* wrow = (const float4*)&wc[k * 16];
            float4 w0 = wrow[0], w1 = wrow[1], w2 = wrow[2], w3 = wrow[3];
            acc[0]  = fmaf(xv, w0.x, acc[0]);  acc[1]  = fmaf(xv, w0.y, acc[1]);
            acc[2]  = fmaf(xv, w0.z, acc[2]);  acc[3]  = fmaf(xv, w0.w, acc[3]);
            acc[4]  = fmaf(xv, w1.x, acc[4]);  acc[5]  = fmaf(xv, w1.y, acc[5]);
            acc[6]  = fmaf(xv, w1.z, acc[6]);  acc[7]  = fmaf(xv, w1.w, acc[7]);
            acc[8]  = fmaf(xv, w2.x, acc[8]);  acc[9]  = fmaf(xv, w2.y, acc[9]);
            acc[10] = fmaf(xv, w2.z, acc[10]); acc[11] = fmaf(xv, w2.w, acc[11]);
            acc[12] = fmaf(xv, w3.x, acc[12]); acc[13] = fmaf(xv, w3.y, acc[13]);
            acc[14] = fmaf(xv, w3.z, acc[14]); acc[15] = fmaf(xv, w3.w, acc[15]);
        }
        __syncthreads();
    }

    if (myRow < n) {
        float4 o0, o1, o2, o3;
        o0 = {acc[0] + B[0], acc[1] + B[1], acc[2] + B[2], acc[3] + B[3]};
        o1 = {acc[4] + B[4], acc[5] + B[5], acc[6] + B[6], acc[7] + B[7]};
        o2 = {acc[8] + B[8], acc[9] + B[9], acc[10] + B[10], acc[11] + B[11]};
        o3 = {acc[12] + B[12], acc[13] + B[13], acc[14] + B[14], acc[15] + B[15]};
        float4* o = (float4*)&H[(size_t)myRow * 16];
        o[0] = o0; o[1] = o1; o[2] = o2; o[3] = o3;
    }
}

// ---------------- aggregation: out[d] = dinv[d]*(dinv[d]*h[d] + sum_s dinv[s]*h[s]) ----------------

template <bool RELU, bool ROWSUM>
__global__ void agg_k(const float* __restrict__ H, const float* __restrict__ dinv,
                      const int* __restrict__ col, const int* __restrict__ rowPtr,
                      const int* __restrict__ cnt, float* __restrict__ out,
                      float* __restrict__ rowsum, int n) {
    int lane = threadIdx.x & 63;
    int node = (blockIdx.x * blockDim.x + threadIdx.x) >> 6;
    if (node >= n) return;
    int f = lane & 15, g = lane >> 4;
    int start = rowPtr[node];
    int c = cnt[node];
    float acc = 0.f, rs = 0.f;
    for (int i = g; i < c; i += 4) {
        int s = col[start + i];
        float w = dinv[s];
        acc = fmaf(w, H[(size_t)s * 16 + f], acc);
        if (ROWSUM) rs += w;
    }
    acc += __shfl_xor(acc, 16, 64);
    acc += __shfl_xor(acc, 32, 64);
    if (ROWSUM) { rs += __shfl_xor(rs, 16, 64); rs += __shfl_xor(rs, 32, 64); }
    float dd = dinv[node];
    if (lane < 16) {
        float v = dd * (acc + dd * H[(size_t)node * 16 + f]);
        if (RELU) v = fmaxf(v, 0.f);
        out[(size_t)node * 16 + f] = v;
    }
    if (ROWSUM && lane == 0) rowsum[node] = dd * (dd + rs);
}

// ---------------- final: logits = a2 @ W2 + rowsum*b2 ; log_softmax ----------------

__global__ void final_k(const float* __restrict__ A2, const float* __restrict__ W2,
                        const float* __restrict__ B2, const float* __restrict__ rowsum,
                        float* __restrict__ out, int n, int nc) {
    int lane = threadIdx.x & 63;
    int node = (blockIdx.x * blockDim.x + threadIdx.x) >> 6;
    if (node >= n) return;
    float a[16];
#pragma unroll
    for (int k = 0; k < 16; k++) a[k] = A2[(size_t)node * 16 + k];
    float logit = -1e30f;
    if (lane < nc) {
        logit = rowsum[node] * B2[lane];
#pragma unroll
        for (int k = 0; k < 16; k++) logit = fmaf(a[k], W2[k * nc + lane], logit);
    }
    float m = logit;
    for (int off = 32; off; off >>= 1) m = fmaxf(m, __shfl_xor(m, off, 64));
    float e = (lane < nc) ? __expf(logit - m) : 0.f;
    float s = e;
    for (int off = 32; off; off >>= 1) s += __shfl_xor(s, off, 64);
    if (lane < nc) out[(size_t)node * nc + lane] = logit - m - __logf(s);
}

// ---------------- launch ----------------

extern "C" void kernel_launch(void* const* d_in, const int* in_sizes, int n_in,
                              void* d_out, int out_size, void* d_ws, size_t ws_size,
                              hipStream_t stream) {
    const float* X  = (const float*)d_in[0];
    const int*   EI = (const int*)d_in[1];
    const float* W1 = (const float*)d_in[2];
    const float* B1 = (const float*)d_in[3];
    const float* W2 = (const float*)d_in[4];
    const float* B2 = (const float*)d_in[5];
    float* out = (float*)d_out;

    int NH = in_sizes[3];            // 16
    int NC = in_sizes[5];            // 40
    int NF = in_sizes[2] / NH;       // 512
    int n  = in_sizes[0] / NF;       // 100000
    int E  = in_sizes[1] / 2;        // 3200000
    const int* src = EI;
    const int* dst = EI + E;

    // workspace layout (256B aligned)
    char* ws = (char*)d_ws;
    size_t o = 0;
    auto alloc = [&](size_t bytes) { size_t r = o; o = (o + bytes + 255) & ~(size_t)255; return r; };
    size_t o_dinv   = alloc((size_t)n * 4);
    size_t o_cntS   = alloc((size_t)n * 4);
    size_t o_cntD   = alloc((size_t)n * 4);
    size_t o_tmp    = alloc((size_t)n * 4);
    size_t o_rowPtr = alloc((size_t)n * 4);
    size_t o_bsum   = alloc(1024);
    size_t o_boff   = alloc(1024);
    size_t o_col    = alloc((size_t)E * 4);
    size_t o_h1     = alloc((size_t)n * 16 * 4);
    size_t o_a1r    = alloc((size_t)n * 16 * 4);
    size_t o_rsum   = alloc((size_t)n * 4);

    float* dinv  = (float*)(ws + o_dinv);
    int* cntS    = (int*)(ws + o_cntS);
    int* cntD    = (int*)(ws + o_cntD);
    int* tmp     = (int*)(ws + o_tmp);
    int* rowPtr  = (int*)(ws + o_rowPtr);
    int* bsum    = (int*)(ws + o_bsum);
    int* boff    = (int*)(ws + o_boff);
    int* col     = (int*)(ws + o_col);
    float* h1    = (float*)(ws + o_h1);
    float* a1r   = (float*)(ws + o_a1r);
    float* a2    = h1;  // alias: h1 is dead after agg1
    float* rsum  = (float*)(ws + o_rsum);

    // zero the three counter arrays (contiguous region cntS..tmp end)
    hipMemsetAsync(ws + o_cntS, 0, o_rowPtr - o_cntS, stream);

    int nb = (n + 1023) / 1024;

    count_k<<<2048, 256, 0, stream>>>(src, dst, cntS, cntD, E);
    dinv_k<<<(n + 255) / 256, 256, 0, stream>>>(cntS, dinv, n);
    scan1_k<<<nb, 256, 0, stream>>>(cntD, bsum, n);
    scan2_k<<<1, 256, 0, stream>>>(bsum, boff, nb);
    scan3_k<<<nb, 256, 0, stream>>>(cntD, boff, rowPtr, n);
    fill_k<<<2048, 256, 0, stream>>>(src, dst, rowPtr, tmp, col, E);

    gemm1_k<<<(n + 255) / 256, 256, 0, stream>>>(X, W1, B1, h1, n);

    int aggGrid = (n + 3) / 4;  // one 64-lane wave per node, 4 waves/block
    agg_k<true, true><<<aggGrid, 256, 0, stream>>>(h1, dinv, col, rowPtr, cntD, a1r, rsum, n);
    agg_k<false, false><<<aggGrid, 256, 0, stream>>>(a1r, dinv, col, rowPtr, cntD, a2, nullptr, n);

    final_k<<<aggGrid, 256, 0, stream>>>(a2, W2, B2, rsum, out, n, NC);
}

// Round 2
// 445.625 us; speedup vs baseline: 1.7688x; 1.7688x over previous
//
#include <hip/hip_runtime.h>
#include <hip/hip_bf16.h>

#define BSH 9
#define BSZ 512  // nodes per bucket

// ---------------- graph build: bucket-sort edges by dst (and src keys by src) ----------------

// Pass 1a: global per-bucket totals via LDS histograms (few global atomics)
__global__ __launch_bounds__(256) void hist_k(const int* __restrict__ src,
                                              const int* __restrict__ dst, int E, int chunk,
                                              int* __restrict__ gbD, int* __restrict__ gbS,
                                              int nbk) {
    __shared__ int lhD[256], lhS[256];
    int t = threadIdx.x;
    lhD[t] = 0; lhS[t] = 0;
    __syncthreads();
    int lo = blockIdx.x * chunk, hi = min(E, lo + chunk);
    for (int i = lo + t; i < hi; i += 256) {
        atomicAdd(&lhD[dst[i] >> BSH], 1);
        atomicAdd(&lhS[src[i] >> BSH], 1);
    }
    __syncthreads();
    if (t < nbk) {
        if (lhD[t]) atomicAdd(&gbD[t], lhD[t]);
        if (lhS[t]) atomicAdd(&gbS[t], lhS[t]);
    }
}

// Pass 1b: exclusive scan of bucket totals -> bases + cursors
__global__ void scanB_k(const int* __restrict__ gbD, const int* __restrict__ gbS,
                        int* __restrict__ baseD, int* __restrict__ curD,
                        int* __restrict__ baseS, int* __restrict__ curS, int nbk) {
    __shared__ int ls[256];
    int t = threadIdx.x;
    int v = (t < nbk) ? gbD[t] : 0;
    ls[t] = v; __syncthreads();
    for (int off = 1; off < 256; off <<= 1) {
        int u = (t >= off) ? ls[t - off] : 0; __syncthreads();
        ls[t] += u; __syncthreads();
    }
    if (t < nbk) { int e = ls[t] - v; baseD[t] = e; curD[t] = e; }
    if (t == 0) baseD[nbk] = ls[nbk - 1];
    __syncthreads();
    int w = (t < nbk) ? gbS[t] : 0;
    ls[t] = w; __syncthreads();
    for (int off = 1; off < 256; off <<= 1) {
        int u = (t >= off) ? ls[t - off] : 0; __syncthreads();
        ls[t] += u; __syncthreads();
    }
    if (t < nbk) { int e = ls[t] - w; baseS[t] = e; curS[t] = e; }
    if (t == 0) baseS[nbk] = ls[nbk - 1];
}

// Pass 1c: scatter (src,dst) pairs into dst-buckets, src keys into src-buckets
__global__ __launch_bounds__(256) void scatter_k(const int* __restrict__ src,
                                                 const int* __restrict__ dst, int E, int chunk,
                                                 int* __restrict__ curD, int* __restrict__ curS,
                                                 int2* __restrict__ pairs, int* __restrict__ sbuf,
                                                 int nbk) {
    __shared__ int lhD[256], lhS[256], bD[256], bS[256];
    int t = threadIdx.x;
    lhD[t] = 0; lhS[t] = 0;
    __syncthreads();
    int lo = blockIdx.x * chunk, hi = min(E, lo + chunk);
    for (int i = lo + t; i < hi; i += 256) {
        atomicAdd(&lhD[dst[i] >> BSH], 1);
        atomicAdd(&lhS[src[i] >> BSH], 1);
    }
    __syncthreads();
    if (t < nbk) {
        bD[t] = lhD[t] ? atomicAdd(&curD[t], lhD[t]) : 0;
        bS[t] = lhS[t] ? atomicAdd(&curS[t], lhS[t]) : 0;
    }
    __syncthreads();
    lhD[t] = 0; lhS[t] = 0;
    __syncthreads();
    for (int i = lo + t; i < hi; i += 256) {  // chunk is L2-hot from first loop
        int s = src[i], d = dst[i];
        int pd = bD[d >> BSH] + atomicAdd(&lhD[d >> BSH], 1);
        pairs[pd] = make_int2(s, d);
        int ps = bS[s >> BSH] + atomicAdd(&lhS[s >> BSH], 1);
        sbuf[ps] = s;
    }
}

// Pass 2 (src): per-bucket src-degree count -> dinv = rsqrt(1+deg)
__global__ __launch_bounds__(256) void dinv2_k(const int* __restrict__ sbuf,
                                               const int* __restrict__ baseS,
                                               float* __restrict__ dinv, int n) {
    __shared__ int cnt[BSZ];
    int b = blockIdx.x, t = threadIdx.x;
    cnt[t] = 0; cnt[t + 256] = 0;
    __syncthreads();
    int lo = baseS[b], hi = baseS[b + 1];
    for (int i = lo + t; i < hi; i += 256) atomicAdd(&cnt[sbuf[i] & (BSZ - 1)], 1);
    __syncthreads();
    int n0 = b * BSZ + t, n1 = n0 + 256;
    if (n0 < n) dinv[n0] = rsqrtf((float)(1 + cnt[t]));
    if (n1 < n) dinv[n1] = rsqrtf((float)(1 + cnt[t + 256]));
}

// Pass 2 (dst): per-bucket CSR build entirely in LDS
__global__ __launch_bounds__(256) void build_k(const int2* __restrict__ pairs,
                                               const int* __restrict__ baseD,
                                               int* __restrict__ rowPtr, int* __restrict__ cntD,
                                               int* __restrict__ col, int n) {
    __shared__ int cnt[BSZ];
    __shared__ int off[BSZ];
    __shared__ int ps[256];
    int b = blockIdx.x, t = threadIdx.x;
    cnt[t] = 0; cnt[t + 256] = 0;
    __syncthreads();
    int lo = baseD[b], hi = baseD[b + 1];
    for (int i = lo + t; i < hi; i += 256) atomicAdd(&cnt[pairs[i].y & (BSZ - 1)], 1);
    __syncthreads();
    int c0 = cnt[2 * t], c1 = cnt[2 * t + 1];
    ps[t] = c0 + c1;
    __syncthreads();
    for (int o = 1; o < 256; o <<= 1) {
        int u = (t >= o) ? ps[t - o] : 0; __syncthreads();
        ps[t] += u; __syncthreads();
    }
    int ex = ps[t] - (c0 + c1);
    off[2 * t] = ex; off[2 * t + 1] = ex + c0;
    __syncthreads();
    int n0 = b * BSZ + t, n1 = n0 + 256;
    if (n0 < n) { rowPtr[n0] = lo + off[t]; cntD[n0] = cnt[t]; }
    if (n1 < n) { rowPtr[n1] = lo + off[t + 256]; cntD[n1] = cnt[t + 256]; }
    __syncthreads();
    cnt[t] = 0; cnt[t + 256] = 0;
    __syncthreads();
    for (int i = lo + t; i < hi; i += 256) {  // L2-hot re-read
        int2 p = pairs[i];
        int l = p.y & (BSZ - 1);
        int pos = lo + off[l] + atomicAdd(&cnt[l], 1);
        col[pos] = p.x;
    }
}

// ---------------- GEMM1: h = X @ W1 + b1  (X: n x 512, W1: 512 x 16) ----------------

#define KCH 32
#define XTS 258  // LDS row stride (floats): conflict-free reads, 2-way writes

__global__ __launch_bounds__(256) void gemm1_k(const float* __restrict__ X,
                                               const float* __restrict__ W,
                                               const float* __restrict__ B,
                                               float* __restrict__ H, int n) {
    __shared__ float xt[KCH * XTS];
    __shared__ float wc[KCH * 16];
    int t = threadIdx.x;
    int rowBase = blockIdx.x * 256;
    int myRow = rowBase + t;
    int srow = t >> 3, skq = t & 7;

    float acc[16];
#pragma unroll
    for (int c = 0; c < 16; c++) acc[c] = 0.f;

    float4 xreg[8];
#pragma unroll
    for (int p = 0; p < 8; p++) {
        int gr = rowBase + p * 32 + srow;
        xreg[p] = (gr < n) ? *(const float4*)&X[(size_t)gr * 512 + skq * 4]
                           : float4{0.f, 0.f, 0.f, 0.f};
    }

    for (int ch = 0; ch < 16; ++ch) {
        int k0 = ch * KCH;
#pragma unroll
        for (int p = 0; p < 8; p++) {
            int r = p * 32 + srow;
            int kb = skq * 4;
            xt[(kb + 0) * XTS + r] = xreg[p].x;
            xt[(kb + 1) * XTS + r] = xreg[p].y;
            xt[(kb + 2) * XTS + r] = xreg[p].z;
            xt[(kb + 3) * XTS + r] = xreg[p].w;
        }
        wc[t] = W[k0 * 16 + t];
        wc[256 + t] = W[k0 * 16 + 256 + t];
        __syncthreads();

        if (ch < 15) {
            int k0n = k0 + KCH;
#pragma unroll
            for (int p = 0; p < 8; p++) {
                int gr = rowBase + p * 32 + srow;
                xreg[p] = (gr < n) ? *(const float4*)&X[(size_t)gr * 512 + k0n + skq * 4]
                                   : float4{0.f, 0.f, 0.f, 0.f};
            }
        }

#pragma unroll
        for (int k = 0; k < KCH; k++) {
            float xv = xt[k * XTS + t];
            const float4* wrow = (const float4*)&wc[k * 16];
            float4 w0 = wrow[0], w1 = wrow[1], w2 = wrow[2], w3 = wrow[3];
            acc[0]  = fmaf(xv, w0.x, acc[0]);  acc[1]  = fmaf(xv, w0.y, acc[1]);
            acc[2]  = fmaf(xv, w0.z, acc[2]);  acc[3]  = fmaf(xv, w0.w, acc[3]);
            acc[4]  = fmaf(xv, w1.x, acc[4]);  acc[5]  = fmaf(xv, w1.y, acc[5]);
            acc[6]  = fmaf(xv, w1.z, acc[6]);  acc[7]  = fmaf(xv, w1.w, acc[7]);
            acc[8]  = fmaf(xv, w2.x, acc[8]);  acc[9]  = fmaf(xv, w2.y, acc[9]);
            acc[10] = fmaf(xv, w2.z, acc[10]); acc[11] = fmaf(xv, w2.w, acc[11]);
            acc[12] = fmaf(xv, w3.x, acc[12]); acc[13] = fmaf(xv, w3.y, acc[13]);
            acc[14] = fmaf(xv, w3.z, acc[14]); acc[15] = fmaf(xv, w3.w, acc[15]);
        }
        __syncthreads();
    }

    if (myRow < n) {
        float4 o0, o1, o2, o3;
        o0 = {acc[0] + B[0], acc[1] + B[1], acc[2] + B[2], acc[3] + B[3]};
        o1 = {acc[4] + B[4], acc[5] + B[5], acc[6] + B[6], acc[7] + B[7]};
        o2 = {acc[8] + B[8], acc[9] + B[9], acc[10] + B[10], acc[11] + B[11]};
        o3 = {acc[12] + B[12], acc[13] + B[13], acc[14] + B[14], acc[15] + B[15]};
        float4* o = (float4*)&H[(size_t)myRow * 16];
        o[0] = o0; o[1] = o1; o[2] = o2; o[3] = o3;
    }
}

// ---------------- aggregation: out[d] = dinv[d]*(dinv[d]*h[d] + sum_s dinv[s]*h[s]) ----------------

template <bool RELU, bool ROWSUM>
__global__ void agg_k(const float* __restrict__ H, const float* __restrict__ dinv,
                      const int* __restrict__ col, const int* __restrict__ rowPtr,
                      const int* __restrict__ cnt, float* __restrict__ out,
                      float* __restrict__ rowsum, int n) {
    int lane = threadIdx.x & 63;
    int node = (blockIdx.x * blockDim.x + threadIdx.x) >> 6;
    if (node >= n) return;
    int f = lane & 15, g = lane >> 4;
    int start = rowPtr[node];
    int c = cnt[node];
    float acc = 0.f, rs = 0.f;
    for (int i = g; i < c; i += 4) {
        int s = col[start + i];
        float w = dinv[s];
        acc = fmaf(w, H[(size_t)s * 16 + f], acc);
        if (ROWSUM) rs += w;
    }
    acc += __shfl_xor(acc, 16, 64);
    acc += __shfl_xor(acc, 32, 64);
    if (ROWSUM) { rs += __shfl_xor(rs, 16, 64); rs += __shfl_xor(rs, 32, 64); }
    float dd = dinv[node];
    if (lane < 16) {
        float v = dd * (acc + dd * H[(size_t)node * 16 + f]);
        if (RELU) v = fmaxf(v, 0.f);
        out[(size_t)node * 16 + f] = v;
    }
    if (ROWSUM && lane == 0) rowsum[node] = dd * (dd + rs);
}

// ---------------- final: logits = a2 @ W2 + rowsum*b2 ; log_softmax ----------------

__global__ void final_k(const float* __restrict__ A2, const float* __restrict__ W2,
                        const float* __restrict__ B2, const float* __restrict__ rowsum,
                        float* __restrict__ out, int n, int nc) {
    int lane = threadIdx.x & 63;
    int node = (blockIdx.x * blockDim.x + threadIdx.x) >> 6;
    if (node >= n) return;
    float a[16];
#pragma unroll
    for (int k = 0; k < 16; k++) a[k] = A2[(size_t)node * 16 + k];
    float logit = -1e30f;
    if (lane < nc) {
        logit = rowsum[node] * B2[lane];
#pragma unroll
        for (int k = 0; k < 16; k++) logit = fmaf(a[k], W2[k * nc + lane], logit);
    }
    float m = logit;
    for (int off = 32; off; off >>= 1) m = fmaxf(m, __shfl_xor(m, off, 64));
    float e = (lane < nc) ? __expf(logit - m) : 0.f;
    float s = e;
    for (int off = 32; off; off >>= 1) s += __shfl_xor(s, off, 64);
    if (lane < nc) out[(size_t)node * nc + lane] = logit - m - __logf(s);
}

// ---------------- launch ----------------

extern "C" void kernel_launch(void* const* d_in, const int* in_sizes, int n_in,
                              void* d_out, int out_size, void* d_ws, size_t ws_size,
                              hipStream_t stream) {
    const float* X  = (const float*)d_in[0];
    const int*   EI = (const int*)d_in[1];
    const float* W1 = (const float*)d_in[2];
    const float* B1 = (const float*)d_in[3];
    const float* W2 = (const float*)d_in[4];
    const float* B2 = (const float*)d_in[5];
    float* out = (float*)d_out;

    int NH = in_sizes[3];            // 16
    int NC = in_sizes[5];            // 40
    int NF = in_sizes[2] / NH;       // 512
    int n  = in_sizes[0] / NF;       // 100000
    int E  = in_sizes[1] / 2;        // 3200000
    const int* src = EI;
    const int* dst = EI + E;
    int nbk = (n + BSZ - 1) >> BSH;  // 196

    char* ws = (char*)d_ws;
    size_t o = 0;
    auto alloc = [&](size_t bytes) { size_t r = o; o = (o + bytes + 255) & ~(size_t)255; return r; };
    size_t o_dinv   = alloc((size_t)n * 4);
    size_t o_rowPtr = alloc((size_t)n * 4);
    size_t o_cntD   = alloc((size_t)n * 4);
    size_t o_rsum   = alloc((size_t)n * 4);
    size_t o_gbD    = alloc(1024);
    size_t o_gbS    = alloc(1024);
    size_t o_baseD  = alloc(1024 + 4);
    size_t o_curD   = alloc(1024);
    size_t o_baseS  = alloc(1024 + 4);
    size_t o_curS   = alloc(1024);
    size_t o_pairs  = alloc((size_t)E * 8);
    size_t o_sbuf   = alloc((size_t)E * 4);   // sbuf (dead after dinv2) then col

    float* dinv  = (float*)(ws + o_dinv);
    int* rowPtr  = (int*)(ws + o_rowPtr);
    int* cntD    = (int*)(ws + o_cntD);
    float* rsum  = (float*)(ws + o_rsum);
    int* gbD     = (int*)(ws + o_gbD);
    int* gbS     = (int*)(ws + o_gbS);
    int* baseD   = (int*)(ws + o_baseD);
    int* curD    = (int*)(ws + o_curD);
    int* baseS   = (int*)(ws + o_baseS);
    int* curS    = (int*)(ws + o_curS);
    int2* pairs  = (int2*)(ws + o_pairs);
    int* sbuf    = (int*)(ws + o_sbuf);
    int* col     = (int*)(ws + o_sbuf);               // alias: sbuf dead before build_k writes col
    float* h1    = (float*)(ws + o_pairs);            // alias: pairs dead after build_k
    float* a1r   = (float*)(ws + o_pairs + (size_t)n * 16 * 4);
    float* a2    = h1;                                // h1 dead after agg1

    hipMemsetAsync(ws + o_gbD, 0, 2048, stream);      // gbD + gbS

    const int NBLK = 512;
    int chunk = (E + NBLK - 1) / NBLK;
    hist_k<<<NBLK, 256, 0, stream>>>(src, dst, E, chunk, gbD, gbS, nbk);
    scanB_k<<<1, 256, 0, stream>>>(gbD, gbS, baseD, curD, baseS, curS, nbk);
    scatter_k<<<NBLK, 256, 0, stream>>>(src, dst, E, chunk, curD, curS, pairs, sbuf, nbk);
    dinv2_k<<<nbk, 256, 0, stream>>>(sbuf, baseS, dinv, n);
    build_k<<<nbk, 256, 0, stream>>>(pairs, baseD, rowPtr, cntD, col, n);

    gemm1_k<<<(n + 255) / 256, 256, 0, stream>>>(X, W1, B1, h1, n);

    int aggGrid = (n + 3) / 4;
    agg_k<true, true><<<aggGrid, 256, 0, stream>>>(h1, dinv, col, rowPtr, cntD, a1r, rsum, n);
    agg_k<false, false><<<aggGrid, 256, 0, stream>>>(a1r, dinv, col, rowPtr, cntD, a2, nullptr, n);

    final_k<<<aggGrid, 256, 0, stream>>>(a2, W2, B2, rsum, out, n, NC);
}

// Round 3
// 322.720 us; speedup vs baseline: 2.4424x; 1.3808x over previous
//
#include <hip/hip_runtime.h>
#include <hip/hip_bf16.h>

#define BSH 9
#define BSZ 512  // nodes per bucket

// ---------------- graph build: bucket-sort edges by dst (and src keys by src) ----------------

__global__ __launch_bounds__(256) void hist_k(const int* __restrict__ src,
                                              const int* __restrict__ dst, int E, int chunk,
                                              int* __restrict__ gbD, int* __restrict__ gbS,
                                              int nbk) {
    __shared__ int lhD[256], lhS[256];
    int t = threadIdx.x;
    lhD[t] = 0; lhS[t] = 0;
    __syncthreads();
    int lo = blockIdx.x * chunk, hi = min(E, lo + chunk);
    for (int i = lo + t; i < hi; i += 256) {
        atomicAdd(&lhD[dst[i] >> BSH], 1);
        atomicAdd(&lhS[src[i] >> BSH], 1);
    }
    __syncthreads();
    if (t < nbk) {
        if (lhD[t]) atomicAdd(&gbD[t], lhD[t]);
        if (lhS[t]) atomicAdd(&gbS[t], lhS[t]);
    }
}

__global__ void scanB_k(const int* __restrict__ gbD, const int* __restrict__ gbS,
                        int* __restrict__ baseD, int* __restrict__ curD,
                        int* __restrict__ baseS, int* __restrict__ curS, int nbk) {
    __shared__ int ls[256];
    int t = threadIdx.x;
    int v = (t < nbk) ? gbD[t] : 0;
    ls[t] = v; __syncthreads();
    for (int off = 1; off < 256; off <<= 1) {
        int u = (t >= off) ? ls[t - off] : 0; __syncthreads();
        ls[t] += u; __syncthreads();
    }
    if (t < nbk) { int e = ls[t] - v; baseD[t] = e; curD[t] = e; }
    if (t == 0) baseD[nbk] = ls[nbk - 1];
    __syncthreads();
    int w = (t < nbk) ? gbS[t] : 0;
    ls[t] = w; __syncthreads();
    for (int off = 1; off < 256; off <<= 1) {
        int u = (t >= off) ? ls[t - off] : 0; __syncthreads();
        ls[t] += u; __syncthreads();
    }
    if (t < nbk) { int e = ls[t] - w; baseS[t] = e; curS[t] = e; }
    if (t == 0) baseS[nbk] = ls[nbk - 1];
}

// pairs packed: (src << 9) | (dst & 511).  sbuf: low 9 bits of src (ushort).
__global__ __launch_bounds__(256) void scatter_k(const int* __restrict__ src,
                                                 const int* __restrict__ dst, int E, int chunk,
                                                 int* __restrict__ curD, int* __restrict__ curS,
                                                 unsigned int* __restrict__ pairs,
                                                 unsigned short* __restrict__ sbuf, int nbk) {
    __shared__ int lhD[256], lhS[256], bD[256], bS[256];
    int t = threadIdx.x;
    lhD[t] = 0; lhS[t] = 0;
    __syncthreads();
    int lo = blockIdx.x * chunk, hi = min(E, lo + chunk);
    for (int i = lo + t; i < hi; i += 256) {
        atomicAdd(&lhD[dst[i] >> BSH], 1);
        atomicAdd(&lhS[src[i] >> BSH], 1);
    }
    __syncthreads();
    if (t < nbk) {
        bD[t] = lhD[t] ? atomicAdd(&curD[t], lhD[t]) : 0;
        bS[t] = lhS[t] ? atomicAdd(&curS[t], lhS[t]) : 0;
    }
    __syncthreads();
    lhD[t] = 0; lhS[t] = 0;
    __syncthreads();
    for (int i = lo + t; i < hi; i += 256) {  // chunk L2-hot from first loop
        int s = src[i], d = dst[i];
        int pd = bD[d >> BSH] + atomicAdd(&lhD[d >> BSH], 1);
        pairs[pd] = ((unsigned int)s << BSH) | (unsigned int)(d & (BSZ - 1));
        int ps = bS[s >> BSH] + atomicAdd(&lhS[s >> BSH], 1);
        sbuf[ps] = (unsigned short)(s & (BSZ - 1));
    }
}

__global__ __launch_bounds__(256) void dinv2_k(const unsigned short* __restrict__ sbuf,
                                               const int* __restrict__ baseS,
                                               float* __restrict__ dinv, int n) {
    __shared__ int cnt[BSZ];
    int b = blockIdx.x, t = threadIdx.x;
    cnt[t] = 0; cnt[t + 256] = 0;
    __syncthreads();
    int lo = baseS[b], hi = baseS[b + 1];
    for (int i = lo + t; i < hi; i += 256) atomicAdd(&cnt[sbuf[i]], 1);
    __syncthreads();
    int n0 = b * BSZ + t, n1 = n0 + 256;
    if (n0 < n) dinv[n0] = rsqrtf((float)(1 + cnt[t]));
    if (n1 < n) dinv[n1] = rsqrtf((float)(1 + cnt[t + 256]));
}

__global__ __launch_bounds__(256) void build_k(const unsigned int* __restrict__ pairs,
                                               const int* __restrict__ baseD,
                                               int* __restrict__ rowPtr, int* __restrict__ cntD,
                                               int* __restrict__ col, int n) {
    __shared__ int cnt[BSZ];
    __shared__ int off[BSZ];
    __shared__ int ps[256];
    int b = blockIdx.x, t = threadIdx.x;
    cnt[t] = 0; cnt[t + 256] = 0;
    __syncthreads();
    int lo = baseD[b], hi = baseD[b + 1];
    for (int i = lo + t; i < hi; i += 256) atomicAdd(&cnt[pairs[i] & (BSZ - 1)], 1);
    __syncthreads();
    int c0 = cnt[2 * t], c1 = cnt[2 * t + 1];
    ps[t] = c0 + c1;
    __syncthreads();
    for (int o = 1; o < 256; o <<= 1) {
        int u = (t >= o) ? ps[t - o] : 0; __syncthreads();
        ps[t] += u; __syncthreads();
    }
    int ex = ps[t] - (c0 + c1);
    off[2 * t] = ex; off[2 * t + 1] = ex + c0;
    __syncthreads();
    int n0 = b * BSZ + t, n1 = n0 + 256;
    if (n0 < n) { rowPtr[n0] = lo + off[t]; cntD[n0] = cnt[t]; }
    if (n1 < n) { rowPtr[n1] = lo + off[t + 256]; cntD[n1] = cnt[t + 256]; }
    __syncthreads();
    cnt[t] = 0; cnt[t + 256] = 0;
    __syncthreads();
    for (int i = lo + t; i < hi; i += 256) {  // L2-hot re-read
        unsigned int p = pairs[i];
        int l = p & (BSZ - 1);
        int pos = lo + off[l] + atomicAdd(&cnt[l], 1);
        col[pos] = (int)(p >> BSH);
    }
}

// ---------------- GEMM1: h = X @ W1 + b1  (X: n x 512, W1: 512 x 16) ----------------

#define KCH 32
#define XTS 258

__global__ __launch_bounds__(256) void gemm1_k(const float* __restrict__ X,
                                               const float* __restrict__ W,
                                               const float* __restrict__ B,
                                               float* __restrict__ H, int n) {
    __shared__ float xt[KCH * XTS];
    __shared__ float wc[KCH * 16];
    int t = threadIdx.x;
    int rowBase = blockIdx.x * 256;
    int myRow = rowBase + t;
    int srow = t >> 3, skq = t & 7;

    float acc[16];
#pragma unroll
    for (int c = 0; c < 16; c++) acc[c] = 0.f;

    float4 xreg[8];
#pragma unroll
    for (int p = 0; p < 8; p++) {
        int gr = rowBase + p * 32 + srow;
        xreg[p] = (gr < n) ? *(const float4*)&X[(size_t)gr * 512 + skq * 4]
                           : float4{0.f, 0.f, 0.f, 0.f};
    }

    for (int ch = 0; ch < 16; ++ch) {
        int k0 = ch * KCH;
#pragma unroll
        for (int p = 0; p < 8; p++) {
            int r = p * 32 + srow;
            int kb = skq * 4;
            xt[(kb + 0) * XTS + r] = xreg[p].x;
            xt[(kb + 1) * XTS + r] = xreg[p].y;
            xt[(kb + 2) * XTS + r] = xreg[p].z;
            xt[(kb + 3) * XTS + r] = xreg[p].w;
        }
        wc[t] = W[k0 * 16 + t];
        wc[256 + t] = W[k0 * 16 + 256 + t];
        __syncthreads();

        if (ch < 15) {
            int k0n = k0 + KCH;
#pragma unroll
            for (int p = 0; p < 8; p++) {
                int gr = rowBase + p * 32 + srow;
                xreg[p] = (gr < n) ? *(const float4*)&X[(size_t)gr * 512 + k0n + skq * 4]
                                   : float4{0.f, 0.f, 0.f, 0.f};
            }
        }

#pragma unroll
        for (int k = 0; k < KCH; k++) {
            float xv = xt[k * XTS + t];
            const float4* wrow = (const float4*)&wc[k * 16];
            float4 w0 = wrow[0], w1 = wrow[1], w2 = wrow[2], w3 = wrow[3];
            acc[0]  = fmaf(xv, w0.x, acc[0]);  acc[1]  = fmaf(xv, w0.y, acc[1]);
            acc[2]  = fmaf(xv, w0.z, acc[2]);  acc[3]  = fmaf(xv, w0.w, acc[3]);
            acc[4]  = fmaf(xv, w1.x, acc[4]);  acc[5]  = fmaf(xv, w1.y, acc[5]);
            acc[6]  = fmaf(xv, w1.z, acc[6]);  acc[7]  = fmaf(xv, w1.w, acc[7]);
            acc[8]  = fmaf(xv, w2.x, acc[8]);  acc[9]  = fmaf(xv, w2.y, acc[9]);
            acc[10] = fmaf(xv, w2.z, acc[10]); acc[11] = fmaf(xv, w2.w, acc[11]);
            acc[12] = fmaf(xv, w3.x, acc[12]); acc[13] = fmaf(xv, w3.y, acc[13]);
            acc[14] = fmaf(xv, w3.z, acc[14]); acc[15] = fmaf(xv, w3.w, acc[15]);
        }
        __syncthreads();
    }

    if (myRow < n) {
        float4 o0, o1, o2, o3;
        o0 = {acc[0] + B[0], acc[1] + B[1], acc[2] + B[2], acc[3] + B[3]};
        o1 = {acc[4] + B[4], acc[5] + B[5], acc[6] + B[6], acc[7] + B[7]};
        o2 = {acc[8] + B[8], acc[9] + B[9], acc[10] + B[10], acc[11] + B[11]};
        o3 = {acc[12] + B[12], acc[13] + B[13], acc[14] + B[14], acc[15] + B[15]};
        float4* o = (float4*)&H[(size_t)myRow * 16];
        o[0] = o0; o[1] = o1; o[2] = o2; o[3] = o3;
    }
}

// ---------------- aggregation, high-MLP: 4 lanes/edge x float4, 16 edges/wave, 2-way unroll ----

// returns fully-reduced (all lanes) acc float4 for this lane's feature quad q, and edge-weight sum
__device__ __forceinline__ void gather_agg(const float* __restrict__ H,
                                           const float* __restrict__ dinv,
                                           const int* __restrict__ col,
                                           int start, int c, int node, float dd,
                                           int eg, int q, float4& A, float& rs) {
    float4 a0 = {0.f, 0.f, 0.f, 0.f}, a1 = {0.f, 0.f, 0.f, 0.f};
    float rs0 = 0.f, rs1 = 0.f;
    int i = eg;
    for (; i + 16 < c; i += 32) {
        int s0 = col[start + i];
        int s1 = col[start + i + 16];
        float w0 = dinv[s0], w1 = dinv[s1];
        float4 h0 = *(const float4*)&H[(size_t)s0 * 16 + q * 4];
        float4 h1 = *(const float4*)&H[(size_t)s1 * 16 + q * 4];
        a0.x = fmaf(w0, h0.x, a0.x); a0.y = fmaf(w0, h0.y, a0.y);
        a0.z = fmaf(w0, h0.z, a0.z); a0.w = fmaf(w0, h0.w, a0.w);
        a1.x = fmaf(w1, h1.x, a1.x); a1.y = fmaf(w1, h1.y, a1.y);
        a1.z = fmaf(w1, h1.z, a1.z); a1.w = fmaf(w1, h1.w, a1.w);
        rs0 += w0; rs1 += w1;
    }
    if (i < c) {
        int s0 = col[start + i];
        float w0 = dinv[s0];
        float4 h0 = *(const float4*)&H[(size_t)s0 * 16 + q * 4];
        a0.x = fmaf(w0, h0.x, a0.x); a0.y = fmaf(w0, h0.y, a0.y);
        a0.z = fmaf(w0, h0.z, a0.z); a0.w = fmaf(w0, h0.w, a0.w);
        rs0 += w0;
    }
    a0.x += a1.x; a0.y += a1.y; a0.z += a1.z; a0.w += a1.w;
    rs0 += rs1;
    if (eg == 0) {  // self loop
        float4 hs = *(const float4*)&H[(size_t)node * 16 + q * 4];
        a0.x = fmaf(dd, hs.x, a0.x); a0.y = fmaf(dd, hs.y, a0.y);
        a0.z = fmaf(dd, hs.z, a0.z); a0.w = fmaf(dd, hs.w, a0.w);
    }
#pragma unroll
    for (int off = 4; off < 64; off <<= 1) {
        a0.x += __shfl_xor(a0.x, off, 64);
        a0.y += __shfl_xor(a0.y, off, 64);
        a0.z += __shfl_xor(a0.z, off, 64);
        a0.w += __shfl_xor(a0.w, off, 64);
        rs0 += __shfl_xor(rs0, off, 64);
    }
    A = a0; rs = rs0;
}

// layer-1 aggregation + relu + rowsum
__global__ void agg1_k(const float* __restrict__ H, const float* __restrict__ dinv,
                       const int* __restrict__ col, const int* __restrict__ rowPtr,
                       const int* __restrict__ cnt, float* __restrict__ out,
                       float* __restrict__ rowsum, int n) {
    int lane = threadIdx.x & 63;
    int node = (blockIdx.x * blockDim.x + threadIdx.x) >> 6;
    if (node >= n) return;
    int eg = lane >> 2, q = lane & 3;
    int start = rowPtr[node], c = cnt[node];
    float dd = dinv[node];
    float4 A; float rs;
    gather_agg(H, dinv, col, start, c, node, dd, eg, q, A, rs);
    if (eg == 0) {
        float4 v;
        v.x = fmaxf(dd * A.x, 0.f); v.y = fmaxf(dd * A.y, 0.f);
        v.z = fmaxf(dd * A.z, 0.f); v.w = fmaxf(dd * A.w, 0.f);
        *(float4*)&out[(size_t)node * 16 + q * 4] = v;
    }
    if (lane == 0) rowsum[node] = dd * (dd + rs);
}

// layer-2 aggregation fused with logits + log_softmax
__global__ void agg2f_k(const float* __restrict__ H, const float* __restrict__ dinv,
                        const int* __restrict__ col, const int* __restrict__ rowPtr,
                        const int* __restrict__ cnt, const float* __restrict__ rowsum,
                        const float* __restrict__ W2, const float* __restrict__ B2,
                        float* __restrict__ out, int n, int nc) {
    int lane = threadIdx.x & 63;
    int node = (blockIdx.x * blockDim.x + threadIdx.x) >> 6;
    if (node >= n) return;
    int eg = lane >> 2, q = lane & 3;
    int start = rowPtr[node], c = cnt[node];
    float dd = dinv[node];
    float4 A; float rs;
    gather_agg(H, dinv, col, start, c, node, dd, eg, q, A, rs);
    A.x *= dd; A.y *= dd; A.z *= dd; A.w *= dd;   // a2 features, all lanes have quad q
    float f[16];
    f[0]  = __shfl(A.x, 0, 64); f[1]  = __shfl(A.y, 0, 64);
    f[2]  = __shfl(A.z, 0, 64); f[3]  = __shfl(A.w, 0, 64);
    f[4]  = __shfl(A.x, 1, 64); f[5]  = __shfl(A.y, 1, 64);
    f[6]  = __shfl(A.z, 1, 64); f[7]  = __shfl(A.w, 1, 64);
    f[8]  = __shfl(A.x, 2, 64); f[9]  = __shfl(A.y, 2, 64);
    f[10] = __shfl(A.z, 2, 64); f[11] = __shfl(A.w, 2, 64);
    f[12] = __shfl(A.x, 3, 64); f[13] = __shfl(A.y, 3, 64);
    f[14] = __shfl(A.z, 3, 64); f[15] = __shfl(A.w, 3, 64);
    float logit = -1e30f;
    if (lane < nc) {
        logit = rowsum[node] * B2[lane];
#pragma unroll
        for (int k = 0; k < 16; k++) logit = fmaf(f[k], W2[k * nc + lane], logit);
    }
    float m = logit;
#pragma unroll
    for (int off = 1; off < 64; off <<= 1) m = fmaxf(m, __shfl_xor(m, off, 64));
    float e = (lane < nc) ? __expf(logit - m) : 0.f;
    float s = e;
#pragma unroll
    for (int off = 1; off < 64; off <<= 1) s += __shfl_xor(s, off, 64);
    if (lane < nc) out[(size_t)node * nc + lane] = logit - m - __logf(s);
}

// ---------------- launch ----------------

extern "C" void kernel_launch(void* const* d_in, const int* in_sizes, int n_in,
                              void* d_out, int out_size, void* d_ws, size_t ws_size,
                              hipStream_t stream) {
    const float* X  = (const float*)d_in[0];
    const int*   EI = (const int*)d_in[1];
    const float* W1 = (const float*)d_in[2];
    const float* B1 = (const float*)d_in[3];
    const float* W2 = (const float*)d_in[4];
    const float* B2 = (const float*)d_in[5];
    float* out = (float*)d_out;

    int NH = in_sizes[3];            // 16
    int NC = in_sizes[5];            // 40
    int NF = in_sizes[2] / NH;       // 512
    int n  = in_sizes[0] / NF;       // 100000
    int E  = in_sizes[1] / 2;        // 3200000
    const int* src = EI;
    const int* dst = EI + E;
    int nbk = (n + BSZ - 1) >> BSH;  // 196

    char* ws = (char*)d_ws;
    size_t o = 0;
    auto alloc = [&](size_t bytes) { size_t r = o; o = (o + bytes + 255) & ~(size_t)255; return r; };
    size_t o_dinv   = alloc((size_t)n * 4);
    size_t o_rowPtr = alloc((size_t)n * 4);
    size_t o_cntD   = alloc((size_t)n * 4);
    size_t o_rsum   = alloc((size_t)n * 4);
    size_t o_gbD    = alloc(1024);
    size_t o_gbS    = alloc(1024);
    size_t o_baseD  = alloc(1024 + 4);
    size_t o_curD   = alloc(1024);
    size_t o_baseS  = alloc(1024 + 4);
    size_t o_curS   = alloc(1024);
    size_t o_pairs  = alloc((size_t)E * 4);           // packed; dead after build_k -> h1
    size_t o_sbuf   = alloc((size_t)E * 2 + ((size_t)n * 64 > (size_t)E * 2 ? (size_t)n * 64 - (size_t)E * 2 : 0));  // sbuf dead after dinv2 -> a1r
    size_t o_col    = alloc((size_t)E * 4);

    float* dinv  = (float*)(ws + o_dinv);
    int* rowPtr  = (int*)(ws + o_rowPtr);
    int* cntD    = (int*)(ws + o_cntD);
    float* rsum  = (float*)(ws + o_rsum);
    int* gbD     = (int*)(ws + o_gbD);
    int* gbS     = (int*)(ws + o_gbS);
    int* baseD   = (int*)(ws + o_baseD);
    int* curD    = (int*)(ws + o_curD);
    int* baseS   = (int*)(ws + o_baseS);
    int* curS    = (int*)(ws + o_curS);
    unsigned int* pairs   = (unsigned int*)(ws + o_pairs);
    unsigned short* sbuf  = (unsigned short*)(ws + o_sbuf);
    int* col     = (int*)(ws + o_col);
    float* h1    = (float*)(ws + o_pairs);   // n*64 B <= E*4 B here (6.4MB <= 12.8MB)
    float* a1r   = (float*)(ws + o_sbuf);    // n*64 B region reserved above

    hipMemsetAsync(ws + o_gbD, 0, 2048, stream);      // gbD + gbS

    const int NBLK = 512;
    int chunk = (E + NBLK - 1) / NBLK;
    hist_k<<<NBLK, 256, 0, stream>>>(src, dst, E, chunk, gbD, gbS, nbk);
    scanB_k<<<1, 256, 0, stream>>>(gbD, gbS, baseD, curD, baseS, curS, nbk);
    scatter_k<<<NBLK, 256, 0, stream>>>(src, dst, E, chunk, curD, curS, pairs, sbuf, nbk);
    dinv2_k<<<nbk, 256, 0, stream>>>(sbuf, baseS, dinv, n);
    build_k<<<nbk, 256, 0, stream>>>(pairs, baseD, rowPtr, cntD, col, n);

    gemm1_k<<<(n + 255) / 256, 256, 0, stream>>>(X, W1, B1, h1, n);

    int aggGrid = (n + 3) / 4;  // one wave per node, 4 waves/block
    agg1_k<<<aggGrid, 256, 0, stream>>>(h1, dinv, col, rowPtr, cntD, a1r, rsum, n);
    agg2f_k<<<aggGrid, 256, 0, stream>>>(a1r, dinv, col, rowPtr, cntD, rsum, W2, B2, out, n, NC);
}

// Round 4
// 320.032 us; speedup vs baseline: 2.4629x; 1.0084x over previous
//
#include <hip/hip_runtime.h>
#include <hip/hip_bf16.h>

#define BSH 9
#define BSZ 512  // nodes per bucket

__global__ void zero_k(int* __restrict__ p, int m) {
    int i = threadIdx.x + blockIdx.x * blockDim.x;
    if (i < m) p[i] = 0;
}

// ---------------- graph build: bucket-sort edges by dst (and src keys by src) ----------------

__global__ __launch_bounds__(256) void hist_k(const int* __restrict__ src,
                                              const int* __restrict__ dst, int E, int chunk,
                                              int* __restrict__ gbD, int* __restrict__ gbS,
                                              int nbk) {
    __shared__ int lhD[256], lhS[256];
    int t = threadIdx.x;
    lhD[t] = 0; lhS[t] = 0;
    __syncthreads();
    int lo = blockIdx.x * chunk, hi = min(E, lo + chunk);
    for (int i = lo + t; i < hi; i += 256) {
        atomicAdd(&lhD[dst[i] >> BSH], 1);
        atomicAdd(&lhS[src[i] >> BSH], 1);
    }
    __syncthreads();
    if (t < nbk) {
        if (lhD[t]) atomicAdd(&gbD[t], lhD[t]);
        if (lhS[t]) atomicAdd(&gbS[t], lhS[t]);
    }
}

__global__ void scanB_k(const int* __restrict__ gbD, const int* __restrict__ gbS,
                        int* __restrict__ baseD, int* __restrict__ curD,
                        int* __restrict__ baseS, int* __restrict__ curS, int nbk) {
    __shared__ int ls[256];
    int t = threadIdx.x;
    int v = (t < nbk) ? gbD[t] : 0;
    ls[t] = v; __syncthreads();
    for (int off = 1; off < 256; off <<= 1) {
        int u = (t >= off) ? ls[t - off] : 0; __syncthreads();
        ls[t] += u; __syncthreads();
    }
    if (t < nbk) { int e = ls[t] - v; baseD[t] = e; curD[t] = e; }
    if (t == 0) baseD[nbk] = ls[nbk - 1];
    __syncthreads();
    int w = (t < nbk) ? gbS[t] : 0;
    ls[t] = w; __syncthreads();
    for (int off = 1; off < 256; off <<= 1) {
        int u = (t >= off) ? ls[t - off] : 0; __syncthreads();
        ls[t] += u; __syncthreads();
    }
    if (t < nbk) { int e = ls[t] - w; baseS[t] = e; curS[t] = e; }
    if (t == 0) baseS[nbk] = ls[nbk - 1];
}

// pairs packed: (src << 9) | (dst & 511).  sbuf: low 9 bits of src (ushort).
__global__ __launch_bounds__(256) void scatter_k(const int* __restrict__ src,
                                                 const int* __restrict__ dst, int E, int chunk,
                                                 int* __restrict__ curD, int* __restrict__ curS,
                                                 unsigned int* __restrict__ pairs,
                                                 unsigned short* __restrict__ sbuf, int nbk) {
    __shared__ int lhD[256], lhS[256], bD[256], bS[256];
    int t = threadIdx.x;
    lhD[t] = 0; lhS[t] = 0;
    __syncthreads();
    int lo = blockIdx.x * chunk, hi = min(E, lo + chunk);
    for (int i = lo + t; i < hi; i += 256) {
        atomicAdd(&lhD[dst[i] >> BSH], 1);
        atomicAdd(&lhS[src[i] >> BSH], 1);
    }
    __syncthreads();
    if (t < nbk) {
        bD[t] = lhD[t] ? atomicAdd(&curD[t], lhD[t]) : 0;
        bS[t] = lhS[t] ? atomicAdd(&curS[t], lhS[t]) : 0;
    }
    __syncthreads();
    lhD[t] = 0; lhS[t] = 0;
    __syncthreads();
    for (int i = lo + t; i < hi; i += 256) {  // chunk L2-hot from first loop
        int s = src[i], d = dst[i];
        int pd = bD[d >> BSH] + atomicAdd(&lhD[d >> BSH], 1);
        pairs[pd] = ((unsigned int)s << BSH) | (unsigned int)(d & (BSZ - 1));
        int ps = bS[s >> BSH] + atomicAdd(&lhS[s >> BSH], 1);
        sbuf[ps] = (unsigned short)(s & (BSZ - 1));
    }
}

__global__ __launch_bounds__(256) void dinv2_k(const unsigned short* __restrict__ sbuf,
                                               const int* __restrict__ baseS,
                                               float* __restrict__ dinv, int n) {
    __shared__ int cnt[BSZ];
    int b = blockIdx.x, t = threadIdx.x;
    cnt[t] = 0; cnt[t + 256] = 0;
    __syncthreads();
    int lo = baseS[b], hi = baseS[b + 1];
    for (int i = lo + t; i < hi; i += 256) atomicAdd(&cnt[sbuf[i]], 1);
    __syncthreads();
    int n0 = b * BSZ + t, n1 = n0 + 256;
    if (n0 < n) dinv[n0] = rsqrtf((float)(1 + cnt[t]));
    if (n1 < n) dinv[n1] = rsqrtf((float)(1 + cnt[t + 256]));
}

// CSR build + rowsum[d] = dd*(dd + sum_{s in N_in(d)} dinv[s])
__global__ __launch_bounds__(256) void build_k(const unsigned int* __restrict__ pairs,
                                               const int* __restrict__ baseD,
                                               const float* __restrict__ dinv,
                                               int* __restrict__ rowPtr, int* __restrict__ cntD,
                                               int* __restrict__ col, float* __restrict__ rowsum,
                                               int n) {
    __shared__ int cnt[BSZ];
    __shared__ int off[BSZ];
    __shared__ int ps[256];
    __shared__ float lsum[BSZ];
    int b = blockIdx.x, t = threadIdx.x;
    cnt[t] = 0; cnt[t + 256] = 0;
    lsum[t] = 0.f; lsum[t + 256] = 0.f;
    __syncthreads();
    int lo = baseD[b], hi = baseD[b + 1];
    for (int i = lo + t; i < hi; i += 256) atomicAdd(&cnt[pairs[i] & (BSZ - 1)], 1);
    __syncthreads();
    int c0 = cnt[2 * t], c1 = cnt[2 * t + 1];
    ps[t] = c0 + c1;
    __syncthreads();
    for (int o = 1; o < 256; o <<= 1) {
        int u = (t >= o) ? ps[t - o] : 0; __syncthreads();
        ps[t] += u; __syncthreads();
    }
    int ex = ps[t] - (c0 + c1);
    off[2 * t] = ex; off[2 * t + 1] = ex + c0;
    __syncthreads();
    int n0 = b * BSZ + t, n1 = n0 + 256;
    if (n0 < n) { rowPtr[n0] = lo + off[t]; cntD[n0] = cnt[t]; }
    if (n1 < n) { rowPtr[n1] = lo + off[t + 256]; cntD[n1] = cnt[t + 256]; }
    __syncthreads();
    cnt[t] = 0; cnt[t + 256] = 0;
    __syncthreads();
    for (int i = lo + t; i < hi; i += 256) {  // L2-hot re-read
        unsigned int p = pairs[i];
        int l = p & (BSZ - 1);
        int s = (int)(p >> BSH);
        int pos = lo + off[l] + atomicAdd(&cnt[l], 1);
        col[pos] = s;
        atomicAdd(&lsum[l], dinv[s]);
    }
    __syncthreads();
    if (n0 < n) { float dd = dinv[n0]; rowsum[n0] = dd * (dd + lsum[t]); }
    if (n1 < n) { float dd = dinv[n1]; rowsum[n1] = dd * (dd + lsum[t + 256]); }
}

// ---------------- GEMM1: hw1 = dinv * (X @ W1 + b1)  (X: n x 512, W1: 512 x 16) ----------------

#define KCH 32
#define XTS 258

__global__ __launch_bounds__(256) void gemm1_k(const float* __restrict__ X,
                                               const float* __restrict__ W,
                                               const float* __restrict__ B,
                                               const float* __restrict__ dinv,
                                               float* __restrict__ H, int n) {
    __shared__ float xt[KCH * XTS];
    __shared__ float wc[KCH * 16];
    int t = threadIdx.x;
    int rowBase = blockIdx.x * 256;
    int myRow = rowBase + t;
    int srow = t >> 3, skq = t & 7;

    float acc[16];
#pragma unroll
    for (int c = 0; c < 16; c++) acc[c] = 0.f;

    float4 xreg[8];
#pragma unroll
    for (int p = 0; p < 8; p++) {
        int gr = rowBase + p * 32 + srow;
        xreg[p] = (gr < n) ? *(const float4*)&X[(size_t)gr * 512 + skq * 4]
                           : float4{0.f, 0.f, 0.f, 0.f};
    }

    for (int ch = 0; ch < 16; ++ch) {
        int k0 = ch * KCH;
#pragma unroll
        for (int p = 0; p < 8; p++) {
            int r = p * 32 + srow;
            int kb = skq * 4;
            xt[(kb + 0) * XTS + r] = xreg[p].x;
            xt[(kb + 1) * XTS + r] = xreg[p].y;
            xt[(kb + 2) * XTS + r] = xreg[p].z;
            xt[(kb + 3) * XTS + r] = xreg[p].w;
        }
        wc[t] = W[k0 * 16 + t];
        wc[256 + t] = W[k0 * 16 + 256 + t];
        __syncthreads();

        if (ch < 15) {
            int k0n = k0 + KCH;
#pragma unroll
            for (int p = 0; p < 8; p++) {
                int gr = rowBase + p * 32 + srow;
                xreg[p] = (gr < n) ? *(const float4*)&X[(size_t)gr * 512 + k0n + skq * 4]
                                   : float4{0.f, 0.f, 0.f, 0.f};
            }
        }

#pragma unroll
        for (int k = 0; k < KCH; k++) {
            float xv = xt[k * XTS + t];
            const float4* wrow = (const float4*)&wc[k * 16];
            float4 w0 = wrow[0], w1 = wrow[1], w2 = wrow[2], w3 = wrow[3];
            acc[0]  = fmaf(xv, w0.x, acc[0]);  acc[1]  = fmaf(xv, w0.y, acc[1]);
            acc[2]  = fmaf(xv, w0.z, acc[2]);  acc[3]  = fmaf(xv, w0.w, acc[3]);
            acc[4]  = fmaf(xv, w1.x, acc[4]);  acc[5]  = fmaf(xv, w1.y, acc[5]);
            acc[6]  = fmaf(xv, w1.z, acc[6]);  acc[7]  = fmaf(xv, w1.w, acc[7]);
            acc[8]  = fmaf(xv, w2.x, acc[8]);  acc[9]  = fmaf(xv, w2.y, acc[9]);
            acc[10] = fmaf(xv, w2.z, acc[10]); acc[11] = fmaf(xv, w2.w, acc[11]);
            acc[12] = fmaf(xv, w3.x, acc[12]); acc[13] = fmaf(xv, w3.y, acc[13]);
            acc[14] = fmaf(xv, w3.z, acc[14]); acc[15] = fmaf(xv, w3.w, acc[15]);
        }
        __syncthreads();
    }

    if (myRow < n) {
        float dv = dinv[myRow];
        float4 o0, o1, o2, o3;
        o0 = {dv * (acc[0] + B[0]), dv * (acc[1] + B[1]), dv * (acc[2] + B[2]), dv * (acc[3] + B[3])};
        o1 = {dv * (acc[4] + B[4]), dv * (acc[5] + B[5]), dv * (acc[6] + B[6]), dv * (acc[7] + B[7])};
        o2 = {dv * (acc[8] + B[8]), dv * (acc[9] + B[9]), dv * (acc[10] + B[10]), dv * (acc[11] + B[11])};
        o3 = {dv * (acc[12] + B[12]), dv * (acc[13] + B[13]), dv * (acc[14] + B[14]), dv * (acc[15] + B[15])};
        float4* o = (float4*)&H[(size_t)myRow * 16];
        o[0] = o0; o[1] = o1; o[2] = o2; o[3] = o3;
    }
}

// ---------------- aggregation on premultiplied features: A[d] = hw[d] + sum_s hw[s] ----------

// returns fully-reduced (all lanes) acc float4 for this lane's feature quad q
__device__ __forceinline__ float4 gather_agg(const float* __restrict__ HW,
                                             const int* __restrict__ col,
                                             int start, int c, int node,
                                             int eg, int q) {
    float4 a0 = {0.f, 0.f, 0.f, 0.f}, a1 = {0.f, 0.f, 0.f, 0.f};
    int i = eg;
    for (; i + 16 < c; i += 32) {
        int s0 = col[start + i];
        int s1 = col[start + i + 16];
        float4 h0 = *(const float4*)&HW[(size_t)s0 * 16 + q * 4];
        float4 h1 = *(const float4*)&HW[(size_t)s1 * 16 + q * 4];
        a0.x += h0.x; a0.y += h0.y; a0.z += h0.z; a0.w += h0.w;
        a1.x += h1.x; a1.y += h1.y; a1.z += h1.z; a1.w += h1.w;
    }
    if (i < c) {
        int s0 = col[start + i];
        float4 h0 = *(const float4*)&HW[(size_t)s0 * 16 + q * 4];
        a0.x += h0.x; a0.y += h0.y; a0.z += h0.z; a0.w += h0.w;
    }
    if (eg == 0) {  // self loop: hw[node] = dinv[node]*h[node]
        float4 hs = *(const float4*)&HW[(size_t)node * 16 + q * 4];
        a1.x += hs.x; a1.y += hs.y; a1.z += hs.z; a1.w += hs.w;
    }
    a0.x += a1.x; a0.y += a1.y; a0.z += a1.z; a0.w += a1.w;
#pragma unroll
    for (int off = 4; off < 64; off <<= 1) {
        a0.x += __shfl_xor(a0.x, off, 64);
        a0.y += __shfl_xor(a0.y, off, 64);
        a0.z += __shfl_xor(a0.z, off, 64);
        a0.w += __shfl_xor(a0.w, off, 64);
    }
    return a0;
}

// layer-1: out = dinv * relu(dinv * A)   (premultiplied for layer 2)
__global__ void agg1_k(const float* __restrict__ HW, const float* __restrict__ dinv,
                       const int* __restrict__ col, const int* __restrict__ rowPtr,
                       const int* __restrict__ cnt, float* __restrict__ out, int n) {
    int lane = threadIdx.x & 63;
    int node = (blockIdx.x * blockDim.x + threadIdx.x) >> 6;
    if (node >= n) return;
    int eg = lane >> 2, q = lane & 3;
    int start = rowPtr[node], c = cnt[node];
    float4 A = gather_agg(HW, col, start, c, node, eg, q);
    if (eg == 0) {
        float dd = dinv[node];
        float4 v;
        v.x = dd * fmaxf(dd * A.x, 0.f); v.y = dd * fmaxf(dd * A.y, 0.f);
        v.z = dd * fmaxf(dd * A.z, 0.f); v.w = dd * fmaxf(dd * A.w, 0.f);
        *(float4*)&out[(size_t)node * 16 + q * 4] = v;
    }
}

// layer-2 aggregation fused with logits + log_softmax
__global__ void agg2f_k(const float* __restrict__ HW, const float* __restrict__ dinv,
                        const int* __restrict__ col, const int* __restrict__ rowPtr,
                        const int* __restrict__ cnt, const float* __restrict__ rowsum,
                        const float* __restrict__ W2, const float* __restrict__ B2,
                        float* __restrict__ out, int n, int nc) {
    int lane = threadIdx.x & 63;
    int node = (blockIdx.x * blockDim.x + threadIdx.x) >> 6;
    if (node >= n) return;
    int eg = lane >> 2, q = lane & 3;
    int start = rowPtr[node], c = cnt[node];
    float4 A = gather_agg(HW, col, start, c, node, eg, q);
    float dd = dinv[node];
    A.x *= dd; A.y *= dd; A.z *= dd; A.w *= dd;   // a2 features, all lanes hold quad q
    float f[16];
    f[0]  = __shfl(A.x, 0, 64); f[1]  = __shfl(A.y, 0, 64);
    f[2]  = __shfl(A.z, 0, 64); f[3]  = __shfl(A.w, 0, 64);
    f[4]  = __shfl(A.x, 1, 64); f[5]  = __shfl(A.y, 1, 64);
    f[6]  = __shfl(A.z, 1, 64); f[7]  = __shfl(A.w, 1, 64);
    f[8]  = __shfl(A.x, 2, 64); f[9]  = __shfl(A.y, 2, 64);
    f[10] = __shfl(A.z, 2, 64); f[11] = __shfl(A.w, 2, 64);
    f[12] = __shfl(A.x, 3, 64); f[13] = __shfl(A.y, 3, 64);
    f[14] = __shfl(A.z, 3, 64); f[15] = __shfl(A.w, 3, 64);
    float logit = -1e30f;
    if (lane < nc) {
        logit = rowsum[node] * B2[lane];
#pragma unroll
        for (int k = 0; k < 16; k++) logit = fmaf(f[k], W2[k * nc + lane], logit);
    }
    float m = logit;
#pragma unroll
    for (int off = 1; off < 64; off <<= 1) m = fmaxf(m, __shfl_xor(m, off, 64));
    float e = (lane < nc) ? __expf(logit - m) : 0.f;
    float s = e;
#pragma unroll
    for (int off = 1; off < 64; off <<= 1) s += __shfl_xor(s, off, 64);
    if (lane < nc) out[(size_t)node * nc + lane] = logit - m - __logf(s);
}

// ---------------- launch ----------------

extern "C" void kernel_launch(void* const* d_in, const int* in_sizes, int n_in,
                              void* d_out, int out_size, void* d_ws, size_t ws_size,
                              hipStream_t stream) {
    const float* X  = (const float*)d_in[0];
    const int*   EI = (const int*)d_in[1];
    const float* W1 = (const float*)d_in[2];
    const float* B1 = (const float*)d_in[3];
    const float* W2 = (const float*)d_in[4];
    const float* B2 = (const float*)d_in[5];
    float* out = (float*)d_out;

    int NH = in_sizes[3];            // 16
    int NC = in_sizes[5];            // 40
    int NF = in_sizes[2] / NH;       // 512
    int n  = in_sizes[0] / NF;       // 100000
    int E  = in_sizes[1] / 2;        // 3200000
    const int* src = EI;
    const int* dst = EI + E;
    int nbk = (n + BSZ - 1) >> BSH;  // 196

    char* ws = (char*)d_ws;
    size_t o = 0;
    auto alloc = [&](size_t bytes) { size_t r = o; o = (o + bytes + 255) & ~(size_t)255; return r; };
    size_t o_dinv   = alloc((size_t)n * 4);
    size_t o_rowPtr = alloc((size_t)n * 4);
    size_t o_cntD   = alloc((size_t)n * 4);
    size_t o_rsum   = alloc((size_t)n * 4);
    size_t o_gbD    = alloc(1024);
    size_t o_gbS    = alloc(1024);
    size_t o_baseD  = alloc(1024 + 4);
    size_t o_curD   = alloc(1024);
    size_t o_baseS  = alloc(1024 + 4);
    size_t o_curS   = alloc(1024);
    size_t o_pairs  = alloc((size_t)E * 4);           // packed; dead after build_k -> hw1
    size_t o_sbuf   = alloc((size_t)E * 2 + ((size_t)n * 64 > (size_t)E * 2 ? (size_t)n * 64 - (size_t)E * 2 : 0));  // sbuf dead after dinv2 -> a1w
    size_t o_col    = alloc((size_t)E * 4);

    float* dinv  = (float*)(ws + o_dinv);
    int* rowPtr  = (int*)(ws + o_rowPtr);
    int* cntD    = (int*)(ws + o_cntD);
    float* rsum  = (float*)(ws + o_rsum);
    int* gbD     = (int*)(ws + o_gbD);
    int* gbS     = (int*)(ws + o_gbS);
    int* baseD   = (int*)(ws + o_baseD);
    int* curD    = (int*)(ws + o_curD);
    int* baseS   = (int*)(ws + o_baseS);
    int* curS    = (int*)(ws + o_curS);
    unsigned int* pairs   = (unsigned int*)(ws + o_pairs);
    unsigned short* sbuf  = (unsigned short*)(ws + o_sbuf);
    int* col     = (int*)(ws + o_col);
    float* hw1   = (float*)(ws + o_pairs);   // n*64 B <= E*4 B (6.4MB <= 12.8MB)
    float* a1w   = (float*)(ws + o_sbuf);    // n*64 B region reserved above

    zero_k<<<1, 512, 0, stream>>>(gbD, 512);  // gbD+gbS contiguous (replaces pathological hipMemsetAsync)

    const int NBLK = 512;
    int chunk = (E + NBLK - 1) / NBLK;
    hist_k<<<NBLK, 256, 0, stream>>>(src, dst, E, chunk, gbD, gbS, nbk);
    scanB_k<<<1, 256, 0, stream>>>(gbD, gbS, baseD, curD, baseS, curS, nbk);
    scatter_k<<<NBLK, 256, 0, stream>>>(src, dst, E, chunk, curD, curS, pairs, sbuf, nbk);
    dinv2_k<<<nbk, 256, 0, stream>>>(sbuf, baseS, dinv, n);
    build_k<<<nbk, 256, 0, stream>>>(pairs, baseD, dinv, rowPtr, cntD, col, rsum, n);

    gemm1_k<<<(n + 255) / 256, 256, 0, stream>>>(X, W1, B1, dinv, hw1, n);

    int aggGrid = (n + 3) / 4;  // one wave per node, 4 waves/block
    agg1_k<<<aggGrid, 256, 0, stream>>>(hw1, dinv, col, rowPtr, cntD, a1w, n);
    agg2f_k<<<aggGrid, 256, 0, stream>>>(a1w, dinv, col, rowPtr, cntD, rsum, W2, B2, out, n, NC);
}

// Round 5
// 292.851 us; speedup vs baseline: 2.6915x; 1.0928x over previous
//
#include <hip/hip_runtime.h>
#include <hip/hip_bf16.h>

#define BSH 9
#define BSZ 512  // nodes per bucket

__device__ __forceinline__ unsigned short f2bf(float f) {  // RN-even fp32->bf16
    unsigned u = __float_as_uint(f);
    u += 0x7fffu + ((u >> 16) & 1u);
    return (unsigned short)(u >> 16);
}
__device__ __forceinline__ float b2f(unsigned short v) {
    return __uint_as_float((unsigned)v << 16);
}

__global__ void zero_k(int* __restrict__ p, int m) {
    int i = threadIdx.x + blockIdx.x * blockDim.x;
    if (i < m) p[i] = 0;
}

// ---------------- graph build: bucket-sort edges by dst (and src keys by src) ----------------

__global__ __launch_bounds__(256) void hist_k(const int* __restrict__ src,
                                              const int* __restrict__ dst, int E, int chunk,
                                              int* __restrict__ gbD, int* __restrict__ gbS,
                                              int nbk) {
    __shared__ int lhD[256], lhS[256];
    int t = threadIdx.x;
    lhD[t] = 0; lhS[t] = 0;
    __syncthreads();
    int lo = blockIdx.x * chunk, hi = min(E, lo + chunk);
    for (int i = lo + t; i < hi; i += 256) {
        atomicAdd(&lhD[dst[i] >> BSH], 1);
        atomicAdd(&lhS[src[i] >> BSH], 1);
    }
    __syncthreads();
    if (t < nbk) {
        if (lhD[t]) atomicAdd(&gbD[t], lhD[t]);
        if (lhS[t]) atomicAdd(&gbS[t], lhS[t]);
    }
}

__global__ void scanB_k(const int* __restrict__ gbD, const int* __restrict__ gbS,
                        int* __restrict__ baseD, int* __restrict__ curD,
                        int* __restrict__ baseS, int* __restrict__ curS, int nbk) {
    __shared__ int ls[256];
    int t = threadIdx.x;
    int v = (t < nbk) ? gbD[t] : 0;
    ls[t] = v; __syncthreads();
    for (int off = 1; off < 256; off <<= 1) {
        int u = (t >= off) ? ls[t - off] : 0; __syncthreads();
        ls[t] += u; __syncthreads();
    }
    if (t < nbk) { int e = ls[t] - v; baseD[t] = e; curD[t] = e; }
    if (t == 0) baseD[nbk] = ls[nbk - 1];
    __syncthreads();
    int w = (t < nbk) ? gbS[t] : 0;
    ls[t] = w; __syncthreads();
    for (int off = 1; off < 256; off <<= 1) {
        int u = (t >= off) ? ls[t - off] : 0; __syncthreads();
        ls[t] += u; __syncthreads();
    }
    if (t < nbk) { int e = ls[t] - w; baseS[t] = e; curS[t] = e; }
    if (t == 0) baseS[nbk] = ls[nbk - 1];
}

// ---------------- fused: GEMM1 (h1 = X@W1 + b1, fp32) + edge scatter ----------------
// blocks [0, nG1): gemm.  blocks [nG1, nG1+NBLK): scatter.
// pairs packed: (src << 9) | (dst & 511).  sbuf: low 9 bits of src (ushort).

#define KCH 32
#define XTS 258

__global__ __launch_bounds__(256) void fused_gs_k(
    const float* __restrict__ X, const float* __restrict__ W, const float* __restrict__ B,
    float* __restrict__ H, int n, int nG1,
    const int* __restrict__ src, const int* __restrict__ dst, int E, int chunk,
    int* __restrict__ curD, int* __restrict__ curS,
    unsigned int* __restrict__ pairs, unsigned short* __restrict__ sbuf, int nbk) {
    __shared__ float xt[KCH * XTS];
    __shared__ float wc[KCH * 16];
    __shared__ int lhD[256], lhS[256], bD[256], bS[256];
    int t = threadIdx.x;

    if ((int)blockIdx.x < nG1) {
        // ---- GEMM path ----
        int rowBase = blockIdx.x * 256;
        int myRow = rowBase + t;
        int srow = t >> 3, skq = t & 7;
        float acc[16];
#pragma unroll
        for (int c = 0; c < 16; c++) acc[c] = 0.f;
        float4 xreg[8];
#pragma unroll
        for (int p = 0; p < 8; p++) {
            int gr = rowBase + p * 32 + srow;
            xreg[p] = (gr < n) ? *(const float4*)&X[(size_t)gr * 512 + skq * 4]
                               : float4{0.f, 0.f, 0.f, 0.f};
        }
        for (int ch = 0; ch < 16; ++ch) {
            int k0 = ch * KCH;
#pragma unroll
            for (int p = 0; p < 8; p++) {
                int r = p * 32 + srow;
                int kb = skq * 4;
                xt[(kb + 0) * XTS + r] = xreg[p].x;
                xt[(kb + 1) * XTS + r] = xreg[p].y;
                xt[(kb + 2) * XTS + r] = xreg[p].z;
                xt[(kb + 3) * XTS + r] = xreg[p].w;
            }
            wc[t] = W[k0 * 16 + t];
            wc[256 + t] = W[k0 * 16 + 256 + t];
            __syncthreads();
            if (ch < 15) {
                int k0n = k0 + KCH;
#pragma unroll
                for (int p = 0; p < 8; p++) {
                    int gr = rowBase + p * 32 + srow;
                    xreg[p] = (gr < n) ? *(const float4*)&X[(size_t)gr * 512 + k0n + skq * 4]
                                       : float4{0.f, 0.f, 0.f, 0.f};
                }
            }
#pragma unroll
            for (int k = 0; k < KCH; k++) {
                float xv = xt[k * XTS + t];
                const float4* wrow = (const float4*)&wc[k * 16];
                float4 w0 = wrow[0], w1 = wrow[1], w2 = wrow[2], w3 = wrow[3];
                acc[0]  = fmaf(xv, w0.x, acc[0]);  acc[1]  = fmaf(xv, w0.y, acc[1]);
                acc[2]  = fmaf(xv, w0.z, acc[2]);  acc[3]  = fmaf(xv, w0.w, acc[3]);
                acc[4]  = fmaf(xv, w1.x, acc[4]);  acc[5]  = fmaf(xv, w1.y, acc[5]);
                acc[6]  = fmaf(xv, w1.z, acc[6]);  acc[7]  = fmaf(xv, w1.w, acc[7]);
                acc[8]  = fmaf(xv, w2.x, acc[8]);  acc[9]  = fmaf(xv, w2.y, acc[9]);
                acc[10] = fmaf(xv, w2.z, acc[10]); acc[11] = fmaf(xv, w2.w, acc[11]);
                acc[12] = fmaf(xv, w3.x, acc[12]); acc[13] = fmaf(xv, w3.y, acc[13]);
                acc[14] = fmaf(xv, w3.z, acc[14]); acc[15] = fmaf(xv, w3.w, acc[15]);
            }
            __syncthreads();
        }
        if (myRow < n) {
            float4 o0 = {acc[0] + B[0], acc[1] + B[1], acc[2] + B[2], acc[3] + B[3]};
            float4 o1 = {acc[4] + B[4], acc[5] + B[5], acc[6] + B[6], acc[7] + B[7]};
            float4 o2 = {acc[8] + B[8], acc[9] + B[9], acc[10] + B[10], acc[11] + B[11]};
            float4 o3 = {acc[12] + B[12], acc[13] + B[13], acc[14] + B[14], acc[15] + B[15]};
            float4* o = (float4*)&H[(size_t)myRow * 16];
            o[0] = o0; o[1] = o1; o[2] = o2; o[3] = o3;
        }
    } else {
        // ---- scatter path ----
        int bb = blockIdx.x - nG1;
        lhD[t] = 0; lhS[t] = 0;
        __syncthreads();
        int lo = bb * chunk, hi = min(E, lo + chunk);
        for (int i = lo + t; i < hi; i += 256) {
            atomicAdd(&lhD[dst[i] >> BSH], 1);
            atomicAdd(&lhS[src[i] >> BSH], 1);
        }
        __syncthreads();
        if (t < nbk) {
            bD[t] = lhD[t] ? atomicAdd(&curD[t], lhD[t]) : 0;
            bS[t] = lhS[t] ? atomicAdd(&curS[t], lhS[t]) : 0;
        }
        __syncthreads();
        lhD[t] = 0; lhS[t] = 0;
        __syncthreads();
        for (int i = lo + t; i < hi; i += 256) {  // chunk L2-hot from first loop
            int s = src[i], d = dst[i];
            int pd = bD[d >> BSH] + atomicAdd(&lhD[d >> BSH], 1);
            pairs[pd] = ((unsigned int)s << BSH) | (unsigned int)(d & (BSZ - 1));
            int ps = bS[s >> BSH] + atomicAdd(&lhS[s >> BSH], 1);
            sbuf[ps] = (unsigned short)(s & (BSZ - 1));
        }
    }
}

// ---------------- dinv + scale h1 -> bf16 hw1 (hw1 = dinv * h1) ----------------

__global__ __launch_bounds__(256) void dinvScale_k(const unsigned short* __restrict__ sbuf,
                                                   const int* __restrict__ baseS,
                                                   const float* __restrict__ h1,
                                                   float* __restrict__ dinv,
                                                   unsigned short* __restrict__ hw1, int n) {
    __shared__ int cnt[BSZ];
    __shared__ float dl[BSZ];
    int b = blockIdx.x, t = threadIdx.x;
    cnt[t] = 0; cnt[t + 256] = 0;
    __syncthreads();
    int lo = baseS[b], hi = baseS[b + 1];
    for (int i = lo + t; i < hi; i += 256) atomicAdd(&cnt[sbuf[i]], 1);
    __syncthreads();
    int n0 = b * BSZ + t, n1 = n0 + 256;
    float d0 = rsqrtf((float)(1 + cnt[t]));
    float d1 = rsqrtf((float)(1 + cnt[t + 256]));
    dl[t] = d0; dl[t + 256] = d1;
    if (n0 < n) dinv[n0] = d0;
    if (n1 < n) dinv[n1] = d1;
    __syncthreads();
    int rows = min(BSZ, n - b * BSZ);
    int lim4 = rows * 4;                      // float4 units in this bucket
    size_t base = (size_t)b * BSZ * 16;
#pragma unroll
    for (int j = 0; j < 8; j++) {
        int i4 = j * 256 + t;
        if (i4 < lim4) {
            float4 v = *(const float4*)&h1[base + (size_t)i4 * 4];
            float d = dl[i4 >> 2];
            ushort4 u;
            u.x = f2bf(v.x * d); u.y = f2bf(v.y * d);
            u.z = f2bf(v.z * d); u.w = f2bf(v.w * d);
            *(ushort4*)&hw1[base + (size_t)i4 * 4] = u;
        }
    }
}

// ---------------- CSR build + rowsum[d] = dd*(dd + sum_{s in N_in(d)} dinv[s]) ----------------

__global__ __launch_bounds__(256) void build_k(const unsigned int* __restrict__ pairs,
                                               const int* __restrict__ baseD,
                                               const float* __restrict__ dinv,
                                               int* __restrict__ rowPtr, int* __restrict__ cntD,
                                               int* __restrict__ col, float* __restrict__ rowsum,
                                               int n) {
    __shared__ int cnt[BSZ];
    __shared__ int off[BSZ];
    __shared__ int ps[256];
    __shared__ float lsum[BSZ];
    int b = blockIdx.x, t = threadIdx.x;
    cnt[t] = 0; cnt[t + 256] = 0;
    lsum[t] = 0.f; lsum[t + 256] = 0.f;
    __syncthreads();
    int lo = baseD[b], hi = baseD[b + 1];
    for (int i = lo + t; i < hi; i += 256) atomicAdd(&cnt[pairs[i] & (BSZ - 1)], 1);
    __syncthreads();
    int c0 = cnt[2 * t], c1 = cnt[2 * t + 1];
    ps[t] = c0 + c1;
    __syncthreads();
    for (int o = 1; o < 256; o <<= 1) {
        int u = (t >= o) ? ps[t - o] : 0; __syncthreads();
        ps[t] += u; __syncthreads();
    }
    int ex = ps[t] - (c0 + c1);
    off[2 * t] = ex; off[2 * t + 1] = ex + c0;
    __syncthreads();
    int n0 = b * BSZ + t, n1 = n0 + 256;
    if (n0 < n) { rowPtr[n0] = lo + off[t]; cntD[n0] = cnt[t]; }
    if (n1 < n) { rowPtr[n1] = lo + off[t + 256]; cntD[n1] = cnt[t + 256]; }
    __syncthreads();
    cnt[t] = 0; cnt[t + 256] = 0;
    __syncthreads();
    for (int i = lo + t; i < hi; i += 256) {  // L2-hot re-read
        unsigned int p = pairs[i];
        int l = p & (BSZ - 1);
        int s = (int)(p >> BSH);
        int pos = lo + off[l] + atomicAdd(&cnt[l], 1);
        col[pos] = s;
        atomicAdd(&lsum[l], dinv[s]);
    }
    __syncthreads();
    if (n0 < n) { float dd = dinv[n0]; rowsum[n0] = dd * (dd + lsum[t]); }
    if (n1 < n) { float dd = dinv[n1]; rowsum[n1] = dd * (dd + lsum[t + 256]); }
}

// ---------------- aggregation on premultiplied bf16 features ----------------
// A[d] = hw[d] + sum_s hw[s];  4 lanes/edge, ushort4 (8B) per lane, 2-way unroll

__device__ __forceinline__ float4 gather_agg(const unsigned short* __restrict__ HW,
                                             const int* __restrict__ col,
                                             int start, int c, int node, int eg, int q) {
    float4 a0 = {0.f, 0.f, 0.f, 0.f}, a1 = {0.f, 0.f, 0.f, 0.f};
    int i = eg;
    for (; i + 16 < c; i += 32) {
        int s0 = col[start + i];
        int s1 = col[start + i + 16];
        ushort4 u0 = *(const ushort4*)&HW[(size_t)s0 * 16 + q * 4];
        ushort4 u1 = *(const ushort4*)&HW[(size_t)s1 * 16 + q * 4];
        a0.x += b2f(u0.x); a0.y += b2f(u0.y); a0.z += b2f(u0.z); a0.w += b2f(u0.w);
        a1.x += b2f(u1.x); a1.y += b2f(u1.y); a1.z += b2f(u1.z); a1.w += b2f(u1.w);
    }
    if (i < c) {
        int s0 = col[start + i];
        ushort4 u0 = *(const ushort4*)&HW[(size_t)s0 * 16 + q * 4];
        a0.x += b2f(u0.x); a0.y += b2f(u0.y); a0.z += b2f(u0.z); a0.w += b2f(u0.w);
    }
    if (eg == 0) {  // self loop
        ushort4 us = *(const ushort4*)&HW[(size_t)node * 16 + q * 4];
        a1.x += b2f(us.x); a1.y += b2f(us.y); a1.z += b2f(us.z); a1.w += b2f(us.w);
    }
    a0.x += a1.x; a0.y += a1.y; a0.z += a1.z; a0.w += a1.w;
#pragma unroll
    for (int off = 4; off < 64; off <<= 1) {
        a0.x += __shfl_xor(a0.x, off, 64);
        a0.y += __shfl_xor(a0.y, off, 64);
        a0.z += __shfl_xor(a0.z, off, 64);
        a0.w += __shfl_xor(a0.w, off, 64);
    }
    return a0;
}

// layer-1: out = bf16( dinv * relu(dinv * A) )   (premultiplied for layer 2)
__global__ void agg1_k(const unsigned short* __restrict__ HW, const float* __restrict__ dinv,
                       const int* __restrict__ col, const int* __restrict__ rowPtr,
                       const int* __restrict__ cnt, unsigned short* __restrict__ out, int n) {
    int lane = threadIdx.x & 63;
    int node = (blockIdx.x * blockDim.x + threadIdx.x) >> 6;
    if (node >= n) return;
    int eg = lane >> 2, q = lane & 3;
    int start = rowPtr[node], c = cnt[node];
    float4 A = gather_agg(HW, col, start, c, node, eg, q);
    if (eg == 0) {
        float dd = dinv[node];
        ushort4 u;
        u.x = f2bf(dd * fmaxf(dd * A.x, 0.f)); u.y = f2bf(dd * fmaxf(dd * A.y, 0.f));
        u.z = f2bf(dd * fmaxf(dd * A.z, 0.f)); u.w = f2bf(dd * fmaxf(dd * A.w, 0.f));
        *(ushort4*)&out[(size_t)node * 16 + q * 4] = u;
    }
}

// layer-2 aggregation fused with logits + log_softmax
__global__ void agg2f_k(const unsigned short* __restrict__ HW, const float* __restrict__ dinv,
                        const int* __restrict__ col, const int* __restrict__ rowPtr,
                        const int* __restrict__ cnt, const float* __restrict__ rowsum,
                        const float* __restrict__ W2, const float* __restrict__ B2,
                        float* __restrict__ out, int n, int nc) {
    int lane = threadIdx.x & 63;
    int node = (blockIdx.x * blockDim.x + threadIdx.x) >> 6;
    if (node >= n) return;
    int eg = lane >> 2, q = lane & 3;
    int start = rowPtr[node], c = cnt[node];
    float4 A = gather_agg(HW, col, start, c, node, eg, q);
    float dd = dinv[node];
    A.x *= dd; A.y *= dd; A.z *= dd; A.w *= dd;   // a2 features, all lanes hold quad q
    float f[16];
    f[0]  = __shfl(A.x, 0, 64); f[1]  = __shfl(A.y, 0, 64);
    f[2]  = __shfl(A.z, 0, 64); f[3]  = __shfl(A.w, 0, 64);
    f[4]  = __shfl(A.x, 1, 64); f[5]  = __shfl(A.y, 1, 64);
    f[6]  = __shfl(A.z, 1, 64); f[7]  = __shfl(A.w, 1, 64);
    f[8]  = __shfl(A.x, 2, 64); f[9]  = __shfl(A.y, 2, 64);
    f[10] = __shfl(A.z, 2, 64); f[11] = __shfl(A.w, 2, 64);
    f[12] = __shfl(A.x, 3, 64); f[13] = __shfl(A.y, 3, 64);
    f[14] = __shfl(A.z, 3, 64); f[15] = __shfl(A.w, 3, 64);
    float logit = -1e30f;
    if (lane < nc) {
        logit = rowsum[node] * B2[lane];
#pragma unroll
        for (int k = 0; k < 16; k++) logit = fmaf(f[k], W2[k * nc + lane], logit);
    }
    float m = logit;
#pragma unroll
    for (int off = 1; off < 64; off <<= 1) m = fmaxf(m, __shfl_xor(m, off, 64));
    float e = (lane < nc) ? __expf(logit - m) : 0.f;
    float s = e;
#pragma unroll
    for (int off = 1; off < 64; off <<= 1) s += __shfl_xor(s, off, 64);
    if (lane < nc) out[(size_t)node * nc + lane] = logit - m - __logf(s);
}

// ---------------- launch ----------------

extern "C" void kernel_launch(void* const* d_in, const int* in_sizes, int n_in,
                              void* d_out, int out_size, void* d_ws, size_t ws_size,
                              hipStream_t stream) {
    const float* X  = (const float*)d_in[0];
    const int*   EI = (const int*)d_in[1];
    const float* W1 = (const float*)d_in[2];
    const float* B1 = (const float*)d_in[3];
    const float* W2 = (const float*)d_in[4];
    const float* B2 = (const float*)d_in[5];
    float* out = (float*)d_out;

    int NH = in_sizes[3];            // 16
    int NC = in_sizes[5];            // 40
    int NF = in_sizes[2] / NH;       // 512
    int n  = in_sizes[0] / NF;       // 100000
    int E  = in_sizes[1] / 2;        // 3200000
    const int* src = EI;
    const int* dst = EI + E;
    int nbk = (n + BSZ - 1) >> BSH;  // 196

    char* ws = (char*)d_ws;
    size_t o = 0;
    auto alloc = [&](size_t bytes) { size_t r = o; o = (o + bytes + 255) & ~(size_t)255; return r; };
    size_t o_dinv   = alloc((size_t)n * 4);
    size_t o_rowPtr = alloc((size_t)n * 4);
    size_t o_cntD   = alloc((size_t)n * 4);
    size_t o_rsum   = alloc((size_t)n * 4);
    size_t o_gbD    = alloc(1024);
    size_t o_gbS    = alloc(1024);
    size_t o_baseD  = alloc(1024 + 4);
    size_t o_curD   = alloc(1024);
    size_t o_baseS  = alloc(1024 + 4);
    size_t o_curS   = alloc(1024);
    size_t o_pairs  = alloc((size_t)E * 4);
    size_t o_sbuf   = alloc((size_t)E * 2);
    size_t o_col    = alloc((size_t)E * 4);
    size_t o_h1     = alloc((size_t)n * 16 * 4);   // fp32 gemm out (pre-scale)
    size_t o_hw1    = alloc((size_t)n * 16 * 2);   // bf16 dinv*h1
    size_t o_a1w    = alloc((size_t)n * 16 * 2);   // bf16 dinv*relu(layer1)

    float* dinv  = (float*)(ws + o_dinv);
    int* rowPtr  = (int*)(ws + o_rowPtr);
    int* cntD    = (int*)(ws + o_cntD);
    float* rsum  = (float*)(ws + o_rsum);
    int* gbD     = (int*)(ws + o_gbD);
    int* gbS     = (int*)(ws + o_gbS);
    int* baseD   = (int*)(ws + o_baseD);
    int* curD    = (int*)(ws + o_curD);
    int* baseS   = (int*)(ws + o_baseS);
    int* curS    = (int*)(ws + o_curS);
    unsigned int* pairs   = (unsigned int*)(ws + o_pairs);
    unsigned short* sbuf  = (unsigned short*)(ws + o_sbuf);
    int* col     = (int*)(ws + o_col);
    float* h1    = (float*)(ws + o_h1);
    unsigned short* hw1 = (unsigned short*)(ws + o_hw1);
    unsigned short* a1w = (unsigned short*)(ws + o_a1w);

    zero_k<<<1, 512, 0, stream>>>(gbD, 512);  // gbD+gbS contiguous

    const int NBLK = 512;
    int chunk = (E + NBLK - 1) / NBLK;
    int nG1 = (n + 255) / 256;
    hist_k<<<NBLK, 256, 0, stream>>>(src, dst, E, chunk, gbD, gbS, nbk);
    scanB_k<<<1, 256, 0, stream>>>(gbD, gbS, baseD, curD, baseS, curS, nbk);
    fused_gs_k<<<nG1 + NBLK, 256, 0, stream>>>(X, W1, B1, h1, n, nG1,
                                               src, dst, E, chunk, curD, curS,
                                               pairs, sbuf, nbk);
    dinvScale_k<<<nbk, 256, 0, stream>>>(sbuf, baseS, h1, dinv, hw1, n);
    build_k<<<nbk, 256, 0, stream>>>(pairs, baseD, dinv, rowPtr, cntD, col, rsum, n);

    int aggGrid = (n + 3) / 4;  // one wave per node, 4 waves/block
    agg1_k<<<aggGrid, 256, 0, stream>>>(hw1, dinv, col, rowPtr, cntD, a1w, n);
    agg2f_k<<<aggGrid, 256, 0, stream>>>(a1w, dinv, col, rowPtr, cntD, rsum, W2, B2, out, n, NC);
}